// Round 19
// baseline (471.581 us; speedup 1.0000x reference)
//
#include <hip/hip_runtime.h>

#define N_NODESC 200000
#define N_EDGESC 3200000
#define N_GRAPHSC 2000
#define NMAXG 256
#define TOPK 30
#define DCAT 97
#define POOLW (TOPK*DCAT) /* 2910 */
#define BUCKW 512
#define NBUCK ((N_NODESC+BUCKW-1)/BUCKW) /* 391 */
#define CAP 10240
#define PCHUNK 4096
#define NPBLK ((N_EDGESC+PCHUNK-1)/PCHUNK) /* 782 */

typedef int  iv4 __attribute__((ext_vector_type(4)));
typedef float fv4 __attribute__((ext_vector_type(4)));

/* single-pass bucket partition with LDS regrouping + folded batch histogram */
__global__ __launch_bounds__(256) void k_part(const int* __restrict__ src, const int* __restrict__ dst,
                                              const int* __restrict__ batch, int* __restrict__ gcount,
                                              int* __restrict__ bcur, unsigned* __restrict__ pairbuf){
  __shared__ int hcnt[NBUCK];
  __shared__ int hbase[NBUCK];
  __shared__ int lofs[NBUCK];
  __shared__ int scan[256];
  __shared__ unsigned lbuf[PCHUNK];
  __shared__ unsigned short bbuf[PCHUNK];
  int blk = blockIdx.x, t = threadIdx.x;
  int nd = blk*256 + t;
  if (nd < N_NODESC) atomicAdd(&gcount[batch[nd]],1);
  int e0 = blk*PCHUNK;
  int e1 = e0 + PCHUNK; if (e1 > N_EDGESC) e1 = N_EDGESC;
  for (int i=t;i<NBUCK;i+=256) hcnt[i]=0;
  unsigned pk[16]; unsigned meta[16];
  __syncthreads();
  #pragma unroll
  for (int i=0;i<4;i++){
    int e = e0 + i*1024 + t*4;
    if (e < e1){
      iv4 d4 = __builtin_nontemporal_load((const iv4*)(dst+e));
      iv4 s4 = __builtin_nontemporal_load((const iv4*)(src+e));
      #pragma unroll
      for (int k=0;k<4;k++){
        int d = (k==0)?d4.x:(k==1)?d4.y:(k==2)?d4.z:d4.w;
        int s = (k==0)?s4.x:(k==1)?s4.y:(k==2)?s4.z:s4.w;
        if (s!=d){
          int bk = d>>9;
          int pl = atomicAdd(&hcnt[bk],1);
          pk[i*4+k]   = ((unsigned)(d&511)<<18)|(unsigned)s;
          meta[i*4+k] = ((unsigned)bk<<13)|(unsigned)pl;
        } else meta[i*4+k] = 0xFFFFFFFFu;
      }
    } else {
      #pragma unroll
      for (int k=0;k<4;k++) meta[i*4+k] = 0xFFFFFFFFu;
    }
  }
  __syncthreads();
  int i0=2*t, i1=2*t+1;
  int h0 = (i0<NBUCK)? hcnt[i0] : 0;
  int h1 = (i1<NBUCK)? hcnt[i1] : 0;
  int sp = h0+h1;
  scan[t]=sp; __syncthreads();
  for (int off=1;off<256;off<<=1){
    int u = (t>=off)? scan[t-off] : 0;
    __syncthreads();
    scan[t]+=u;
    __syncthreads();
  }
  int ex = scan[t]-sp;
  if (i0<NBUCK) lofs[i0]=ex;
  if (i1<NBUCK) lofs[i1]=ex+h0;
  for (int i=t;i<NBUCK;i+=256){
    int c = hcnt[i];
    hbase[i] = c ? (i*CAP + atomicAdd(&bcur[i],c)) : 0;
  }
  __syncthreads();
  #pragma unroll
  for (int k=0;k<16;k++){
    unsigned m = meta[k];
    if (m != 0xFFFFFFFFu){
      int bk = (int)(m>>13);
      int j = lofs[bk] + (int)(m & 0x1FFFu);
      lbuf[j] = pk[k];
      bbuf[j] = (unsigned short)bk;
    }
  }
  __syncthreads();
  int tot = lofs[NBUCK-1] + hcnt[NBUCK-1];
  for (int j=t; j<tot; j+=256){
    int bk = bbuf[j];
    int addr = hbase[bk] + (j - lofs[bk]);
    if (addr < (bk+1)*CAP) pairbuf[addr] = lbuf[j];
  }
}

/* per-bucket counting sort -> degc, offs, dis, grouped CSR slice */
__global__ __launch_bounds__(512) void k_bsort(const unsigned* __restrict__ pairbuf, const int* __restrict__ bcur,
                                               int* __restrict__ degc, int* __restrict__ offs,
                                               float* __restrict__ dis, int* __restrict__ csr){
  __shared__ int lcsr[CAP];
  __shared__ int lcnt[512];
  __shared__ int lofs[512];
  __shared__ int lcur[512];
  __shared__ int red[512];
  int b = blockIdx.x, t = threadIdx.x;
  int cnt_b = bcur[b]; if (cnt_b > CAP) cnt_b = CAP;
  int pv = 0;
  if (t < b){ int c = bcur[t]; if (c>CAP) c=CAP; pv = c; }
  red[t]=pv; __syncthreads();
  for (int off=256;off>0;off>>=1){ if (t<off) red[t]+=red[t+off]; __syncthreads(); }
  int base = red[0];
  const unsigned* pb = pairbuf + (size_t)b*CAP;
  lcnt[t]=0; __syncthreads();
  for (int i=t;i<cnt_b;i+=512) atomicAdd(&lcnt[pb[i]>>18],1);
  __syncthreads();
  lofs[t]=lcnt[t]; __syncthreads();
  for (int off=1;off<512;off<<=1){
    int u = (t>=off)? lofs[t-off] : 0;
    __syncthreads();
    lofs[t]+=u;
    __syncthreads();
  }
  int excl = lofs[t]-lcnt[t];
  int node = b*BUCKW + t;
  if (node < N_NODESC){
    degc[node] = lcnt[t];
    offs[node] = base + excl;
    dis[node]  = rsqrtf((float)lcnt[t] + 1.0f);
  }
  lcur[t]=excl;
  __syncthreads();
  for (int i=t;i<cnt_b;i+=512){
    unsigned v = pb[i];
    int p = atomicAdd(&lcur[v>>18],1);
    lcsr[p] = (int)(v & 0x3FFFFu);
  }
  __syncthreads();
  for (int i=t;i<cnt_b;i+=512) csr[base+i]=lcsr[i];
}

/* hw1[r][:] = (X[r] @ W1) * dis[r].  LDS-tiled staging, thread-per-row. */
template<int KIN>
__global__ __launch_bounds__(256) void k_mm(const float* __restrict__ X, const float* __restrict__ W,
                                            const float* __restrict__ dis, float* __restrict__ out){
  __shared__ float xs[256*33];
  int r0 = blockIdx.x*256;
  int t = threadIdx.x;
  int r = r0 + t;
  float acc[32];
  #pragma unroll
  for (int f=0;f<32;f++) acc[f]=0.f;
  for (int kc=0; kc<KIN; kc+=32){
    __syncthreads();
    #pragma unroll
    for (int it=0; it<8; it++){
      int idx = it*256 + t;
      int row = idx>>3, c4 = idx&7;
      int gr = r0 + row;
      fv4 v = {0.f,0.f,0.f,0.f};
      if (gr < N_NODESC) v = __builtin_nontemporal_load((const fv4*)(X + (size_t)gr*KIN + kc + c4*4));
      int bofs = row*33 + c4*4;
      xs[bofs]=v.x; xs[bofs+1]=v.y; xs[bofs+2]=v.z; xs[bofs+3]=v.w;
    }
    __syncthreads();
    const float* w0 = W + kc*32;
    const float* xrow = xs + t*33;
    #pragma unroll
    for (int k=0;k<32;k++){
      float xv = xrow[k];
      #pragma unroll
      for (int f=0;f<32;f++) acc[f] = fmaf(xv, w0[k*32+f], acc[f]);
    }
  }
  if (r >= N_NODESC) return;
  float d = dis[r];
  float4* op = (float4*)(out + (size_t)r*32);
  #pragma unroll
  for (int f4=0;f4<8;f4++)
    op[f4] = make_float4(acc[4*f4]*d, acc[4*f4+1]*d, acc[4*f4+2]*d, acc[4*f4+3]*d);
}

/* fused agg + next-layer GEMM, wave-local LDS epilogue:
   x[n][f]   = tanh( dis[n]*(sum_src hws[src][f] + hws[n][f]) + b[f] )
   hwn[n][f] = dis[n] * sum_k x[n][k]*Wn[k][f]
   xls row is written and read by the SAME 32-lane group (same wave):
   threadfence_block (lgkmcnt drain) + wave lockstep => no __syncthreads,
   so no cross-node straggler coupling at the end. */
__global__ __launch_bounds__(256) void k_aggFL(const float* __restrict__ hws, const int* __restrict__ csr,
                      const int* __restrict__ off, const int* __restrict__ cnt,
                      const float* __restrict__ dis, const float* __restrict__ bias,
                      const float* __restrict__ Wn,
                      float* __restrict__ xout, float* __restrict__ hwn){
  __shared__ float Ws[1024];
  __shared__ float xls[8][32];
  int t = threadIdx.x;
  for (int i=t;i<1024;i+=256) Ws[i]=Wn[i];
  __syncthreads();              /* Ws visible; at kernel start, no straggler cost */
  int gt = blockIdx.x*256 + t;
  int n = gt>>5;
  int ln = t>>5;
  int f = t&31;
  int beg = off[n], c = cnt[n];
  float a0=0.f,a1=0.f,a2=0.f,a3=0.f,a4=0.f,a5=0.f,a6=0.f,a7=0.f;
  for (int base=0; base<c; base+=32){
    int m = c-base; if (m>32) m=32;
    int idx = (f<m)? csr[beg+base+f] : 0;
    int j=0;
    for (; j+8<=m; j+=8){
      int s0=__shfl(idx,j,32),   s1=__shfl(idx,j+1,32),
          s2=__shfl(idx,j+2,32), s3=__shfl(idx,j+3,32),
          s4=__shfl(idx,j+4,32), s5=__shfl(idx,j+5,32),
          s6=__shfl(idx,j+6,32), s7=__shfl(idx,j+7,32);
      float v0=hws[(size_t)s0*32+f];
      float v1=hws[(size_t)s1*32+f];
      float v2=hws[(size_t)s2*32+f];
      float v3=hws[(size_t)s3*32+f];
      float v4=hws[(size_t)s4*32+f];
      float v5=hws[(size_t)s5*32+f];
      float v6=hws[(size_t)s6*32+f];
      float v7=hws[(size_t)s7*32+f];
      a0+=v0; a1+=v1; a2+=v2; a3+=v3; a4+=v4; a5+=v5; a6+=v6; a7+=v7;
    }
    for (; j+4<=m; j+=4){
      int s0=__shfl(idx,j,32), s1=__shfl(idx,j+1,32),
          s2=__shfl(idx,j+2,32), s3=__shfl(idx,j+3,32);
      float v0=hws[(size_t)s0*32+f];
      float v1=hws[(size_t)s1*32+f];
      float v2=hws[(size_t)s2*32+f];
      float v3=hws[(size_t)s3*32+f];
      a0+=v0; a1+=v1; a2+=v2; a3+=v3;
    }
    for (; j<m; j++){
      int s0=__shfl(idx,j,32);
      a0 += hws[(size_t)s0*32+f];
    }
  }
  float dn = dis[n];
  float sum = ((a0+a1)+(a2+a3)) + ((a4+a5)+(a6+a7));
  float xv = tanhf(dn*(sum+hws[(size_t)n*32+f]) + bias[f]);
  xout[(size_t)n*32+f] = xv;
  xls[ln][f] = xv;
  __threadfence_block();        /* drain LDS write; wave lockstep covers peers */
  const float* xr = xls[ln];
  float acc=0.f;
  #pragma unroll
  for (int k=0;k<32;k++) acc = fmaf(xr[k], Ws[k*32+f], acc);
  hwn[(size_t)n*32+f] = acc*dn;
}

/* fused layer-3 agg + 32->1 GEMM (x3 out + hw4 = (x3@W4)*dis) */
__global__ __launch_bounds__(256) void k_aggF1(const float* __restrict__ hws, const int* __restrict__ csr,
                      const int* __restrict__ off, const int* __restrict__ cnt,
                      const float* __restrict__ dis, const float* __restrict__ bias,
                      const float* __restrict__ W4,
                      float* __restrict__ xout, float* __restrict__ hw4){
  __shared__ float Ws[32];
  int t = threadIdx.x;
  if (t<32) Ws[t]=W4[t];
  __syncthreads();
  int gt = blockIdx.x*256 + t;
  int n = gt>>5;
  if (n>=N_NODESC) return;
  int f = gt&31;
  int beg = off[n], c = cnt[n];
  float a0=0.f,a1=0.f,a2=0.f,a3=0.f,a4=0.f,a5=0.f,a6=0.f,a7=0.f;
  for (int base=0; base<c; base+=32){
    int m = c-base; if (m>32) m=32;
    int idx = (f<m)? csr[beg+base+f] : 0;
    int j=0;
    for (; j+8<=m; j+=8){
      int s0=__shfl(idx,j,32),   s1=__shfl(idx,j+1,32),
          s2=__shfl(idx,j+2,32), s3=__shfl(idx,j+3,32),
          s4=__shfl(idx,j+4,32), s5=__shfl(idx,j+5,32),
          s6=__shfl(idx,j+6,32), s7=__shfl(idx,j+7,32);
      float v0=hws[(size_t)s0*32+f];
      float v1=hws[(size_t)s1*32+f];
      float v2=hws[(size_t)s2*32+f];
      float v3=hws[(size_t)s3*32+f];
      float v4=hws[(size_t)s4*32+f];
      float v5=hws[(size_t)s5*32+f];
      float v6=hws[(size_t)s6*32+f];
      float v7=hws[(size_t)s7*32+f];
      a0+=v0; a1+=v1; a2+=v2; a3+=v3; a4+=v4; a5+=v5; a6+=v6; a7+=v7;
    }
    for (; j+4<=m; j+=4){
      int s0=__shfl(idx,j,32), s1=__shfl(idx,j+1,32),
          s2=__shfl(idx,j+2,32), s3=__shfl(idx,j+3,32);
      float v0=hws[(size_t)s0*32+f];
      float v1=hws[(size_t)s1*32+f];
      float v2=hws[(size_t)s2*32+f];
      float v3=hws[(size_t)s3*32+f];
      a0+=v0; a1+=v1; a2+=v2; a3+=v3;
    }
    for (; j<m; j++){
      int s0=__shfl(idx,j,32);
      a0 += hws[(size_t)s0*32+f];
    }
  }
  float dn = dis[n];
  float sum = ((a0+a1)+(a2+a3)) + ((a4+a5)+(a6+a7));
  float xv = tanhf(dn*(sum+hws[(size_t)n*32+f]) + bias[f]);
  xout[(size_t)n*32+f] = xv;
  float acc = xv*Ws[f];
  #pragma unroll
  for (int off2=16;off2>0;off2>>=1) acc += __shfl_xor(acc, off2, 32);
  if (f==0) hw4[n] = acc*dn;
}

/* fused tail: per-graph x4 agg + rank top-30 + pool-in-LDS + head.
   fc1 split across all 256 threads; logits parallelized. */
__global__ __launch_bounds__(256) void k_tail(const float* __restrict__ x1,const float* __restrict__ x2,const float* __restrict__ x3,
                       const float* __restrict__ hw4, const int* __restrict__ csr,
                       const int* __restrict__ offs, const int* __restrict__ degc,
                       const float* __restrict__ dis, const float* __restrict__ b4,
                       const int* __restrict__ gcount,
                       const float* __restrict__ cw5, const float* __restrict__ cb5,
                       const float* __restrict__ cw6, const float* __restrict__ cb6,
                       const float* __restrict__ fw1, const float* __restrict__ fb1,
                       const float* __restrict__ fw2, const float* __restrict__ fb2,
                       float* __restrict__ out){
  __shared__ float vals[NMAXG];
  __shared__ int sel[TOPK];
  __shared__ int redsum[256];
  __shared__ float P[POOLW];
  __shared__ float o5[16*30];
  __shared__ float m[16*15];
  __shared__ float o6[32*11];
  __shared__ float o1h[256];
  __shared__ float o1[128];
  __shared__ float lred[160];
  __shared__ float logits[10];
  int g=blockIdx.x, t=threadIdx.x;
  int part=0;
  for (int i=t;i<g;i+=256) part += gcount[i];
  redsum[t]=part; __syncthreads();
  for (int off=128;off>0;off>>=1){ if (t<off) redsum[t]+=redsum[t+off]; __syncthreads(); }
  int start = redsum[0];
  int cntg = gcount[g]; if (cntg>NMAXG) cntg=NMAXG;
  float v=0.f;
  if (t<cntg){
    int n = start+t;
    int beg=offs[n], c=degc[n];
    float a0=0.f,a1=0.f,a2=0.f,a3=0.f;
    int e=0;
    for (; e+4<=c; e+=4){
      int s0=csr[beg+e], s1=csr[beg+e+1], s2=csr[beg+e+2], s3=csr[beg+e+3];
      a0+=hw4[s0]; a1+=hw4[s1]; a2+=hw4[s2]; a3+=hw4[s3];
    }
    for (; e<c; e++) a0+=hw4[csr[beg+e]];
    v = tanhf(dis[n]*(((a0+a1)+(a2+a3))+hw4[n]) + b4[0]);
  }
  vals[t]=v; __syncthreads();
  if (t<cntg){
    int rank=0;
    for (int j=0;j<cntg;j++){
      float vj=vals[j];
      rank += (vj>v) || (vj==v && j<t);
    }
    if (rank<TOPK) sel[rank]=t;
  }
  __syncthreads();
  int nsel = cntg<TOPK?cntg:TOPK;
  for (int idx=t; idx<POOLW; idx+=256){
    int r = idx/DCAT, c = idx - r*DCAT;
    float val=0.f;
    if (r<nsel){
      int node = start + sel[r];
      if (c<32) val = x1[(size_t)node*32+c];
      else if (c<64) val = x2[(size_t)node*32+(c-32)];
      else if (c<96) val = x3[(size_t)node*32+(c-64)];
      else val = vals[sel[r]];
    }
    P[idx]=val;
  }
  __syncthreads();
  for (int i=t;i<480;i+=256){
    int o=i/30, k=i-o*30;
    float acc=cb5[o];
    const float* w=cw5+o*97;
    const float* p=P+k*97;
    #pragma unroll 4
    for(int c=0;c<97;c++) acc = fmaf(p[c], w[c], acc);
    o5[o*30+k]=fmaxf(acc,0.f);
  }
  __syncthreads();
  for (int i=t;i<240;i+=256){
    int o=i/15,k=i-o*15;
    m[i]=fmaxf(o5[o*30+2*k], o5[o*30+2*k+1]);
  }
  __syncthreads();
  for (int i=t;i<352;i+=256){
    int o2=i/11, k=i-o2*11;
    float acc=cb6[o2];
    const float* w=cw6+o2*80;
    #pragma unroll
    for(int ii=0;ii<16;ii++)
      #pragma unroll
      for(int r=0;r<5;r++)
        acc = fmaf(m[ii*15+k+r], w[ii*5+r], acc);
    o6[o2*11+k]=fmaxf(acc,0.f);
  }
  __syncthreads();
  {
    int half = t>>7, tt = t&127;
    int ibeg = half*176;
    float acc = 0.f;
    #pragma unroll 8
    for (int i=ibeg;i<ibeg+176;i++) acc = fmaf(o6[i], fw1[i*128+tt], acc);
    o1h[t] = acc;
  }
  __syncthreads();
  if (t<128) o1[t] = fmaxf(o1h[t]+o1h[128+t]+fb1[t], 0.f);
  __syncthreads();
  if (t<160){
    int c=t>>4, p=t&15;
    float acc=0.f;
    #pragma unroll
    for (int j=p*8;j<p*8+8;j++) acc = fmaf(o1[j], fw2[j*10+c], acc);
    lred[t]=acc;
  }
  __syncthreads();
  if (t<10){
    float acc=fb2[t];
    #pragma unroll
    for (int p=0;p<16;p++) acc += lred[t*16+p];
    logits[t]=acc;
  }
  __syncthreads();
  if (t==0){
    float mx=logits[0];
    for(int c=1;c<10;c++) mx=fmaxf(mx,logits[c]);
    float s=0.f;
    for(int c=0;c<10;c++) s+=expf(logits[c]-mx);
    float lse=logf(s)+mx;
    for(int c=0;c<10;c++) out[(size_t)g*10+c]=logits[c]-lse;
  }
}

extern "C" void kernel_launch(void* const* d_in, const int* in_sizes, int n_in,
                              void* d_out, int out_size, void* d_ws, size_t ws_size,
                              hipStream_t stream){
  const float* x    = (const float*)d_in[0];
  const int*   ei   = (const int*)d_in[1];
  const int*   batch= (const int*)d_in[2];
  const float* W1=(const float*)d_in[3]; const float* b1=(const float*)d_in[4];
  const float* W2=(const float*)d_in[5]; const float* b2=(const float*)d_in[6];
  const float* W3=(const float*)d_in[7]; const float* b3=(const float*)d_in[8];
  const float* W4=(const float*)d_in[9]; const float* b4=(const float*)d_in[10];
  const float* cw5=(const float*)d_in[11]; const float* cb5=(const float*)d_in[12];
  const float* cw6=(const float*)d_in[13]; const float* cb6=(const float*)d_in[14];
  const float* fw1=(const float*)d_in[15]; const float* fb1=(const float*)d_in[16];
  const float* fw2=(const float*)d_in[17]; const float* fb2=(const float*)d_in[18];
  float* out=(float*)d_out;
  const int* src = ei;
  const int* dst = ei + N_EDGESC;

  char* ws=(char*)d_ws;
  size_t o=0;
  auto alloc=[&](size_t nbytes)->char*{ char* p=ws+o; o += (nbytes+255)&~(size_t)255; return p; };
  float* dis    = (float*)alloc((size_t)N_NODESC*4);
  int*   offs   = (int*)alloc((size_t)N_NODESC*4);
  int*   degc   = (int*)alloc((size_t)N_NODESC*4);
  int*   bcur   = (int*)alloc((size_t)NBUCK*4);        /* adjacent to gcount: one memset */
  int*   gcount = (int*)alloc((size_t)N_GRAPHSC*4);
  unsigned* pairbuf = (unsigned*)alloc((size_t)NBUCK*CAP*4);
  int*   csr    = (int*)alloc((size_t)N_EDGESC*4);
  float* x1 = (float*)alloc((size_t)N_NODESC*32*4);
  float* x2 = (float*)alloc((size_t)N_NODESC*32*4);
  float* x3 = (float*)alloc((size_t)N_NODESC*32*4);
  float* hwA = (float*)alloc((size_t)N_NODESC*32*4);
  float* hwB = (float*)alloc((size_t)N_NODESC*32*4);
  float* hw4 = (float*)alloc((size_t)N_NODESC*4);

  /* one memset covers bcur (rounded to 256B) + gcount */
  size_t mset = (((size_t)NBUCK*4+255)&~(size_t)255) + (size_t)N_GRAPHSC*4;
  (void)hipMemsetAsync(bcur, 0, mset, stream);

  int gN = (N_NODESC+255)/256;

  k_part<<<NPBLK,256,0,stream>>>(src,dst,batch,gcount,bcur,pairbuf);
  k_bsort<<<NBUCK,512,0,stream>>>(pairbuf,bcur,degc,offs,dis,csr);

  int gMM = N_NODESC/8; /* 25000 blocks x 8 nodes = exactly 200000 */
  k_mm<128><<<gN,256,0,stream>>>(x, W1, dis, hwA);
  k_aggFL<<<gMM,256,0,stream>>>(hwA,csr,offs,degc,dis,b1,W2,x1,hwB);
  k_aggFL<<<gMM,256,0,stream>>>(hwB,csr,offs,degc,dis,b2,W3,x2,hwA);
  k_aggF1<<<gMM,256,0,stream>>>(hwA,csr,offs,degc,dis,b3,W4,x3,hw4);

  k_tail<<<N_GRAPHSC,256,0,stream>>>(x1,x2,x3,hw4,csr,offs,degc,dis,b4,gcount,
                                     cw5,cb5,cw6,cb6,fw1,fb1,fw2,fb2,out);
}

// Round 20
// 458.597 us; speedup vs baseline: 1.0283x; 1.0283x over previous
//
#include <hip/hip_runtime.h>

#define N_NODESC 200000
#define N_EDGESC 3200000
#define N_GRAPHSC 2000
#define NMAXG 256
#define TOPK 30
#define DCAT 97
#define POOLW (TOPK*DCAT) /* 2910 */
#define BUCKW 512
#define NBUCK ((N_NODESC+BUCKW-1)/BUCKW) /* 391 */
#define CAP 10240
#define PCHUNK 4096
#define NPBLK ((N_EDGESC+PCHUNK-1)/PCHUNK) /* 782 */

typedef int  iv4 __attribute__((ext_vector_type(4)));
typedef float fv4 __attribute__((ext_vector_type(4)));

/* single-pass bucket partition with LDS regrouping + folded batch histogram */
__global__ __launch_bounds__(256) void k_part(const int* __restrict__ src, const int* __restrict__ dst,
                                              const int* __restrict__ batch, int* __restrict__ gcount,
                                              int* __restrict__ bcur, unsigned* __restrict__ pairbuf){
  __shared__ int hcnt[NBUCK];
  __shared__ int hbase[NBUCK];
  __shared__ int lofs[NBUCK];
  __shared__ int scan[256];
  __shared__ unsigned lbuf[PCHUNK];
  __shared__ unsigned short bbuf[PCHUNK];
  int blk = blockIdx.x, t = threadIdx.x;
  int nd = blk*256 + t;
  if (nd < N_NODESC) atomicAdd(&gcount[batch[nd]],1);
  int e0 = blk*PCHUNK;
  int e1 = e0 + PCHUNK; if (e1 > N_EDGESC) e1 = N_EDGESC;
  for (int i=t;i<NBUCK;i+=256) hcnt[i]=0;
  unsigned pk[16]; unsigned meta[16];
  __syncthreads();
  #pragma unroll
  for (int i=0;i<4;i++){
    int e = e0 + i*1024 + t*4;
    if (e < e1){
      iv4 d4 = __builtin_nontemporal_load((const iv4*)(dst+e));
      iv4 s4 = __builtin_nontemporal_load((const iv4*)(src+e));
      #pragma unroll
      for (int k=0;k<4;k++){
        int d = (k==0)?d4.x:(k==1)?d4.y:(k==2)?d4.z:d4.w;
        int s = (k==0)?s4.x:(k==1)?s4.y:(k==2)?s4.z:s4.w;
        if (s!=d){
          int bk = d>>9;
          int pl = atomicAdd(&hcnt[bk],1);
          pk[i*4+k]   = ((unsigned)(d&511)<<18)|(unsigned)s;
          meta[i*4+k] = ((unsigned)bk<<13)|(unsigned)pl;
        } else meta[i*4+k] = 0xFFFFFFFFu;
      }
    } else {
      #pragma unroll
      for (int k=0;k<4;k++) meta[i*4+k] = 0xFFFFFFFFu;
    }
  }
  __syncthreads();
  int i0=2*t, i1=2*t+1;
  int h0 = (i0<NBUCK)? hcnt[i0] : 0;
  int h1 = (i1<NBUCK)? hcnt[i1] : 0;
  int sp = h0+h1;
  scan[t]=sp; __syncthreads();
  for (int off=1;off<256;off<<=1){
    int u = (t>=off)? scan[t-off] : 0;
    __syncthreads();
    scan[t]+=u;
    __syncthreads();
  }
  int ex = scan[t]-sp;
  if (i0<NBUCK) lofs[i0]=ex;
  if (i1<NBUCK) lofs[i1]=ex+h0;
  for (int i=t;i<NBUCK;i+=256){
    int c = hcnt[i];
    hbase[i] = c ? (i*CAP + atomicAdd(&bcur[i],c)) : 0;
  }
  __syncthreads();
  #pragma unroll
  for (int k=0;k<16;k++){
    unsigned m = meta[k];
    if (m != 0xFFFFFFFFu){
      int bk = (int)(m>>13);
      int j = lofs[bk] + (int)(m & 0x1FFFu);
      lbuf[j] = pk[k];
      bbuf[j] = (unsigned short)bk;
    }
  }
  __syncthreads();
  int tot = lofs[NBUCK-1] + hcnt[NBUCK-1];
  for (int j=t; j<tot; j+=256){
    int bk = bbuf[j];
    int addr = hbase[bk] + (j - lofs[bk]);
    if (addr < (bk+1)*CAP) pairbuf[addr] = lbuf[j];
  }
}

/* per-bucket counting sort -> degc, offs, dis, grouped CSR slice */
__global__ __launch_bounds__(512) void k_bsort(const unsigned* __restrict__ pairbuf, const int* __restrict__ bcur,
                                               int* __restrict__ degc, int* __restrict__ offs,
                                               float* __restrict__ dis, int* __restrict__ csr){
  __shared__ int lcsr[CAP];
  __shared__ int lcnt[512];
  __shared__ int lofs[512];
  __shared__ int lcur[512];
  __shared__ int red[512];
  int b = blockIdx.x, t = threadIdx.x;
  int cnt_b = bcur[b]; if (cnt_b > CAP) cnt_b = CAP;
  int pv = 0;
  if (t < b){ int c = bcur[t]; if (c>CAP) c=CAP; pv = c; }
  red[t]=pv; __syncthreads();
  for (int off=256;off>0;off>>=1){ if (t<off) red[t]+=red[t+off]; __syncthreads(); }
  int base = red[0];
  const unsigned* pb = pairbuf + (size_t)b*CAP;
  lcnt[t]=0; __syncthreads();
  for (int i=t;i<cnt_b;i+=512) atomicAdd(&lcnt[pb[i]>>18],1);
  __syncthreads();
  lofs[t]=lcnt[t]; __syncthreads();
  for (int off=1;off<512;off<<=1){
    int u = (t>=off)? lofs[t-off] : 0;
    __syncthreads();
    lofs[t]+=u;
    __syncthreads();
  }
  int excl = lofs[t]-lcnt[t];
  int node = b*BUCKW + t;
  if (node < N_NODESC){
    degc[node] = lcnt[t];
    offs[node] = base + excl;
    dis[node]  = rsqrtf((float)lcnt[t] + 1.0f);
  }
  lcur[t]=excl;
  __syncthreads();
  for (int i=t;i<cnt_b;i+=512){
    unsigned v = pb[i];
    int p = atomicAdd(&lcur[v>>18],1);
    lcsr[p] = (int)(v & 0x3FFFFu);
  }
  __syncthreads();
  for (int i=t;i<cnt_b;i+=512) csr[base+i]=lcsr[i];
}

/* hw1[r][:] = (X[r] @ W1) * dis[r].  LDS-tiled staging, thread-per-row. */
template<int KIN>
__global__ __launch_bounds__(256) void k_mm(const float* __restrict__ X, const float* __restrict__ W,
                                            const float* __restrict__ dis, float* __restrict__ out){
  __shared__ float xs[256*33];
  int r0 = blockIdx.x*256;
  int t = threadIdx.x;
  int r = r0 + t;
  float acc[32];
  #pragma unroll
  for (int f=0;f<32;f++) acc[f]=0.f;
  for (int kc=0; kc<KIN; kc+=32){
    __syncthreads();
    #pragma unroll
    for (int it=0; it<8; it++){
      int idx = it*256 + t;
      int row = idx>>3, c4 = idx&7;
      int gr = r0 + row;
      fv4 v = {0.f,0.f,0.f,0.f};
      if (gr < N_NODESC) v = __builtin_nontemporal_load((const fv4*)(X + (size_t)gr*KIN + kc + c4*4));
      int bofs = row*33 + c4*4;
      xs[bofs]=v.x; xs[bofs+1]=v.y; xs[bofs+2]=v.z; xs[bofs+3]=v.w;
    }
    __syncthreads();
    const float* w0 = W + kc*32;
    const float* xrow = xs + t*33;
    #pragma unroll
    for (int k=0;k<32;k++){
      float xv = xrow[k];
      #pragma unroll
      for (int f=0;f<32;f++) acc[f] = fmaf(xv, w0[k*32+f], acc[f]);
    }
  }
  if (r >= N_NODESC) return;
  float d = dis[r];
  float4* op = (float4*)(out + (size_t)r*32);
  #pragma unroll
  for (int f4=0;f4<8;f4++)
    op[f4] = make_float4(acc[4*f4]*d, acc[4*f4+1]*d, acc[4*f4+2]*d, acc[4*f4+3]*d);
}

/* fused agg + next-layer GEMM, wave-local LDS epilogue (no end barrier) */
__global__ __launch_bounds__(256) void k_aggFL(const float* __restrict__ hws, const int* __restrict__ csr,
                      const int* __restrict__ off, const int* __restrict__ cnt,
                      const float* __restrict__ dis, const float* __restrict__ bias,
                      const float* __restrict__ Wn,
                      float* __restrict__ xout, float* __restrict__ hwn){
  __shared__ float Ws[1024];
  __shared__ float xls[8][32];
  int t = threadIdx.x;
  for (int i=t;i<1024;i+=256) Ws[i]=Wn[i];
  __syncthreads();
  int gt = blockIdx.x*256 + t;
  int n = gt>>5;
  int ln = t>>5;
  int f = t&31;
  int beg = off[n], c = cnt[n];
  float a0=0.f,a1=0.f,a2=0.f,a3=0.f,a4=0.f,a5=0.f,a6=0.f,a7=0.f;
  for (int base=0; base<c; base+=32){
    int m = c-base; if (m>32) m=32;
    int idx = (f<m)? csr[beg+base+f] : 0;
    int j=0;
    for (; j+8<=m; j+=8){
      int s0=__shfl(idx,j,32),   s1=__shfl(idx,j+1,32),
          s2=__shfl(idx,j+2,32), s3=__shfl(idx,j+3,32),
          s4=__shfl(idx,j+4,32), s5=__shfl(idx,j+5,32),
          s6=__shfl(idx,j+6,32), s7=__shfl(idx,j+7,32);
      float v0=hws[(size_t)s0*32+f];
      float v1=hws[(size_t)s1*32+f];
      float v2=hws[(size_t)s2*32+f];
      float v3=hws[(size_t)s3*32+f];
      float v4=hws[(size_t)s4*32+f];
      float v5=hws[(size_t)s5*32+f];
      float v6=hws[(size_t)s6*32+f];
      float v7=hws[(size_t)s7*32+f];
      a0+=v0; a1+=v1; a2+=v2; a3+=v3; a4+=v4; a5+=v5; a6+=v6; a7+=v7;
    }
    for (; j+4<=m; j+=4){
      int s0=__shfl(idx,j,32), s1=__shfl(idx,j+1,32),
          s2=__shfl(idx,j+2,32), s3=__shfl(idx,j+3,32);
      float v0=hws[(size_t)s0*32+f];
      float v1=hws[(size_t)s1*32+f];
      float v2=hws[(size_t)s2*32+f];
      float v3=hws[(size_t)s3*32+f];
      a0+=v0; a1+=v1; a2+=v2; a3+=v3;
    }
    for (; j<m; j++){
      int s0=__shfl(idx,j,32);
      a0 += hws[(size_t)s0*32+f];
    }
  }
  float dn = dis[n];
  float sum = ((a0+a1)+(a2+a3)) + ((a4+a5)+(a6+a7));
  float xv = tanhf(dn*(sum+hws[(size_t)n*32+f]) + bias[f]);
  xout[(size_t)n*32+f] = xv;
  xls[ln][f] = xv;
  __threadfence_block();
  const float* xr = xls[ln];
  float acc=0.f;
  #pragma unroll
  for (int k=0;k<32;k++) acc = fmaf(xr[k], Ws[k*32+f], acc);
  hwn[(size_t)n*32+f] = acc*dn;
}

/* fused layer-3 agg + 32->1 GEMM (x3 out + hw4 = (x3@W4)*dis) */
__global__ __launch_bounds__(256) void k_aggF1(const float* __restrict__ hws, const int* __restrict__ csr,
                      const int* __restrict__ off, const int* __restrict__ cnt,
                      const float* __restrict__ dis, const float* __restrict__ bias,
                      const float* __restrict__ W4,
                      float* __restrict__ xout, float* __restrict__ hw4){
  __shared__ float Ws[32];
  int t = threadIdx.x;
  if (t<32) Ws[t]=W4[t];
  __syncthreads();
  int gt = blockIdx.x*256 + t;
  int n = gt>>5;
  if (n>=N_NODESC) return;
  int f = gt&31;
  int beg = off[n], c = cnt[n];
  float a0=0.f,a1=0.f,a2=0.f,a3=0.f,a4=0.f,a5=0.f,a6=0.f,a7=0.f;
  for (int base=0; base<c; base+=32){
    int m = c-base; if (m>32) m=32;
    int idx = (f<m)? csr[beg+base+f] : 0;
    int j=0;
    for (; j+8<=m; j+=8){
      int s0=__shfl(idx,j,32),   s1=__shfl(idx,j+1,32),
          s2=__shfl(idx,j+2,32), s3=__shfl(idx,j+3,32),
          s4=__shfl(idx,j+4,32), s5=__shfl(idx,j+5,32),
          s6=__shfl(idx,j+6,32), s7=__shfl(idx,j+7,32);
      float v0=hws[(size_t)s0*32+f];
      float v1=hws[(size_t)s1*32+f];
      float v2=hws[(size_t)s2*32+f];
      float v3=hws[(size_t)s3*32+f];
      float v4=hws[(size_t)s4*32+f];
      float v5=hws[(size_t)s5*32+f];
      float v6=hws[(size_t)s6*32+f];
      float v7=hws[(size_t)s7*32+f];
      a0+=v0; a1+=v1; a2+=v2; a3+=v3; a4+=v4; a5+=v5; a6+=v6; a7+=v7;
    }
    for (; j+4<=m; j+=4){
      int s0=__shfl(idx,j,32), s1=__shfl(idx,j+1,32),
          s2=__shfl(idx,j+2,32), s3=__shfl(idx,j+3,32);
      float v0=hws[(size_t)s0*32+f];
      float v1=hws[(size_t)s1*32+f];
      float v2=hws[(size_t)s2*32+f];
      float v3=hws[(size_t)s3*32+f];
      a0+=v0; a1+=v1; a2+=v2; a3+=v3;
    }
    for (; j<m; j++){
      int s0=__shfl(idx,j,32);
      a0 += hws[(size_t)s0*32+f];
    }
  }
  float dn = dis[n];
  float sum = ((a0+a1)+(a2+a3)) + ((a4+a5)+(a6+a7));
  float xv = tanhf(dn*(sum+hws[(size_t)n*32+f]) + bias[f]);
  xout[(size_t)n*32+f] = xv;
  float acc = xv*Ws[f];
  #pragma unroll
  for (int off2=16;off2>0;off2>>=1) acc += __shfl_xor(acc, off2, 32);
  if (f==0) hw4[n] = acc*dn;
}

/* fused tail (round-17 version): per-graph x4 agg + rank top-30 + pool-in-LDS + head */
__global__ __launch_bounds__(256) void k_tail(const float* __restrict__ x1,const float* __restrict__ x2,const float* __restrict__ x3,
                       const float* __restrict__ hw4, const int* __restrict__ csr,
                       const int* __restrict__ offs, const int* __restrict__ degc,
                       const float* __restrict__ dis, const float* __restrict__ b4,
                       const int* __restrict__ gcount,
                       const float* __restrict__ cw5, const float* __restrict__ cb5,
                       const float* __restrict__ cw6, const float* __restrict__ cb6,
                       const float* __restrict__ fw1, const float* __restrict__ fb1,
                       const float* __restrict__ fw2, const float* __restrict__ fb2,
                       float* __restrict__ out){
  __shared__ float vals[NMAXG];
  __shared__ int sel[TOPK];
  __shared__ int redsum[256];
  __shared__ float P[POOLW];
  __shared__ float o5[16*30];
  __shared__ float m[16*15];
  __shared__ float o6[32*11];
  __shared__ float o1[128];
  __shared__ float logits[10];
  int g=blockIdx.x, t=threadIdx.x;
  int part=0;
  for (int i=t;i<g;i+=256) part += gcount[i];
  redsum[t]=part; __syncthreads();
  for (int off=128;off>0;off>>=1){ if (t<off) redsum[t]+=redsum[t+off]; __syncthreads(); }
  int start = redsum[0];
  int cntg = gcount[g]; if (cntg>NMAXG) cntg=NMAXG;
  float v=0.f;
  if (t<cntg){
    int n = start+t;
    int beg=offs[n], c=degc[n];
    float a0=0.f,a1=0.f,a2=0.f,a3=0.f;
    int e=0;
    for (; e+4<=c; e+=4){
      int s0=csr[beg+e], s1=csr[beg+e+1], s2=csr[beg+e+2], s3=csr[beg+e+3];
      a0+=hw4[s0]; a1+=hw4[s1]; a2+=hw4[s2]; a3+=hw4[s3];
    }
    for (; e<c; e++) a0+=hw4[csr[beg+e]];
    v = tanhf(dis[n]*(((a0+a1)+(a2+a3))+hw4[n]) + b4[0]);
  }
  vals[t]=v; __syncthreads();
  if (t<cntg){
    int rank=0;
    for (int j=0;j<cntg;j++){
      float vj=vals[j];
      rank += (vj>v) || (vj==v && j<t);
    }
    if (rank<TOPK) sel[rank]=t;
  }
  __syncthreads();
  int nsel = cntg<TOPK?cntg:TOPK;
  for (int idx=t; idx<POOLW; idx+=256){
    int r = idx/DCAT, c = idx - r*DCAT;
    float val=0.f;
    if (r<nsel){
      int node = start + sel[r];
      if (c<32) val = x1[(size_t)node*32+c];
      else if (c<64) val = x2[(size_t)node*32+(c-32)];
      else if (c<96) val = x3[(size_t)node*32+(c-64)];
      else val = vals[sel[r]];
    }
    P[idx]=val;
  }
  __syncthreads();
  for (int i=t;i<480;i+=256){
    int o=i/30, k=i-o*30;
    float acc=cb5[o];
    const float* w=cw5+o*97;
    const float* p=P+k*97;
    for(int c=0;c<97;c++) acc = fmaf(p[c], w[c], acc);
    o5[o*30+k]=fmaxf(acc,0.f);
  }
  __syncthreads();
  for (int i=t;i<240;i+=256){
    int o=i/15,k=i-o*15;
    m[i]=fmaxf(o5[o*30+2*k], o5[o*30+2*k+1]);
  }
  __syncthreads();
  for (int i=t;i<352;i+=256){
    int o2=i/11, k=i-o2*11;
    float acc=cb6[o2];
    const float* w=cw6+o2*80;
    #pragma unroll
    for(int ii=0;ii<16;ii++)
      #pragma unroll
      for(int r=0;r<5;r++)
        acc = fmaf(m[ii*15+k+r], w[ii*5+r], acc);
    o6[o2*11+k]=fmaxf(acc,0.f);
  }
  __syncthreads();
  if (t<128){
    float acc=fb1[t];
    for(int i=0;i<352;i++) acc = fmaf(o6[i], fw1[i*128+t], acc);
    o1[t]=fmaxf(acc,0.f);
  }
  __syncthreads();
  if (t<10){
    float acc=fb2[t];
    for(int j=0;j<128;j++) acc = fmaf(o1[j], fw2[j*10+t], acc);
    logits[t]=acc;
  }
  __syncthreads();
  if (t==0){
    float mx=logits[0];
    for(int c=1;c<10;c++) mx=fmaxf(mx,logits[c]);
    float s=0.f;
    for(int c=0;c<10;c++) s+=expf(logits[c]-mx);
    float lse=logf(s)+mx;
    for(int c=0;c<10;c++) out[(size_t)g*10+c]=logits[c]-lse;
  }
}

extern "C" void kernel_launch(void* const* d_in, const int* in_sizes, int n_in,
                              void* d_out, int out_size, void* d_ws, size_t ws_size,
                              hipStream_t stream){
  const float* x    = (const float*)d_in[0];
  const int*   ei   = (const int*)d_in[1];
  const int*   batch= (const int*)d_in[2];
  const float* W1=(const float*)d_in[3]; const float* b1=(const float*)d_in[4];
  const float* W2=(const float*)d_in[5]; const float* b2=(const float*)d_in[6];
  const float* W3=(const float*)d_in[7]; const float* b3=(const float*)d_in[8];
  const float* W4=(const float*)d_in[9]; const float* b4=(const float*)d_in[10];
  const float* cw5=(const float*)d_in[11]; const float* cb5=(const float*)d_in[12];
  const float* cw6=(const float*)d_in[13]; const float* cb6=(const float*)d_in[14];
  const float* fw1=(const float*)d_in[15]; const float* fb1=(const float*)d_in[16];
  const float* fw2=(const float*)d_in[17]; const float* fb2=(const float*)d_in[18];
  float* out=(float*)d_out;
  const int* src = ei;
  const int* dst = ei + N_EDGESC;

  char* ws=(char*)d_ws;
  size_t o=0;
  auto alloc=[&](size_t nbytes)->char*{ char* p=ws+o; o += (nbytes+255)&~(size_t)255; return p; };
  float* dis    = (float*)alloc((size_t)N_NODESC*4);
  int*   offs   = (int*)alloc((size_t)N_NODESC*4);
  int*   degc   = (int*)alloc((size_t)N_NODESC*4);
  int*   bcur   = (int*)alloc((size_t)NBUCK*4);        /* adjacent to gcount: one memset */
  int*   gcount = (int*)alloc((size_t)N_GRAPHSC*4);
  unsigned* pairbuf = (unsigned*)alloc((size_t)NBUCK*CAP*4);
  int*   csr    = (int*)alloc((size_t)N_EDGESC*4);
  float* x1 = (float*)alloc((size_t)N_NODESC*32*4);
  float* x2 = (float*)alloc((size_t)N_NODESC*32*4);
  float* x3 = (float*)alloc((size_t)N_NODESC*32*4);
  float* hwA = (float*)alloc((size_t)N_NODESC*32*4);
  float* hwB = (float*)alloc((size_t)N_NODESC*32*4);
  float* hw4 = (float*)alloc((size_t)N_NODESC*4);

  /* one memset covers bcur (rounded to 256B) + gcount */
  size_t mset = (((size_t)NBUCK*4+255)&~(size_t)255) + (size_t)N_GRAPHSC*4;
  (void)hipMemsetAsync(bcur, 0, mset, stream);

  int gN = (N_NODESC+255)/256;

  k_part<<<NPBLK,256,0,stream>>>(src,dst,batch,gcount,bcur,pairbuf);
  k_bsort<<<NBUCK,512,0,stream>>>(pairbuf,bcur,degc,offs,dis,csr);

  int gMM = N_NODESC/8; /* 25000 blocks x 8 nodes = exactly 200000 */
  k_mm<128><<<gN,256,0,stream>>>(x, W1, dis, hwA);
  k_aggFL<<<gMM,256,0,stream>>>(hwA,csr,offs,degc,dis,b1,W2,x1,hwB);
  k_aggFL<<<gMM,256,0,stream>>>(hwB,csr,offs,degc,dis,b2,W3,x2,hwA);
  k_aggF1<<<gMM,256,0,stream>>>(hwA,csr,offs,degc,dis,b3,W4,x3,hw4);

  k_tail<<<N_GRAPHSC,256,0,stream>>>(x1,x2,x3,hw4,csr,offs,degc,dis,b4,gcount,
                                     cw5,cb5,cw6,cb6,fw1,fb1,fw2,fb2,out);
}